// Round 5
// baseline (354.831 us; speedup 1.0000x reference)
//
#include <hip/hip_runtime.h>
#include <hip/hip_bf16.h>

// Problem sizes (fixed)
#define B_    8
#define C_    256
#define NPIX  16384           // 128*128
#define BK    64
#define KC4   16              // K-chunks for gram
#define KCH4  (NPIX / KC4)    // 1024 k per block
#define NSTEP4 (KCH4 / BK)    // 16 steps per block

typedef __attribute__((ext_vector_type(8))) short bf16x8;
typedef __attribute__((ext_vector_type(4))) float f32x4;
typedef unsigned int uint_;

__device__ __forceinline__ unsigned short f2bf(float x) {
  unsigned int u = __builtin_bit_cast(unsigned int, x);
  u = (u + 0x7fffu + ((u >> 16) & 1u)) >> 16;   // RTNE
  return (unsigned short)u;
}
__device__ __forceinline__ float fcomp(const float4& v, int i) {
  switch (i) { case 0: return v.x; case 1: return v.y; case 2: return v.z; default: return v.w; }
}

// ---------------- k_gram: partial Gram, NO atomics (unchanged, r4) ---------
__global__ __launch_bounds__(512, 2) void k_gram(const float* __restrict__ x,
                                                 float* __restrict__ gpart,
                                                 float* __restrict__ spart) {
  const int bid  = blockIdx.x;
  const int half = bid >> 7;
  const int b    = (bid >> 4) & 7;
  const int kc   = bid & 15;
  const float* X = x + (size_t)b * C_ * NPIX + kc * KCH4;

  __shared__ __align__(16) unsigned short Hi[2][256 * 64];
  __shared__ __align__(16) unsigned short Lo[2][256 * 64];

  const int tid  = threadIdx.x;
  const int lane = tid & 63;
  const int w    = tid >> 6;
  const int wr   = w >> 2;
  const int wc   = w & 3;

  const int srow = tid >> 4;
  const int scol = (tid & 15) * 4;
  const float* sp = X + (size_t)srow * NPIX + scol;

  float rs[8] = {};
  float4 g[8];

#define GLOAD(ks)                                                             \
  _Pragma("unroll")                                                           \
  for (int j = 0; j < 8; ++j)                                                 \
    g[j] = *reinterpret_cast<const float4*>(sp + (size_t)j * 32 * NPIX + (ks) * BK);

#define STAGE(buf)                                                            \
  _Pragma("unroll")                                                           \
  for (int j = 0; j < 8; ++j) {                                               \
    const float4 v = g[j];                                                    \
    rs[j] += (v.x + v.y) + (v.z + v.w);                                       \
    const uint_ u0 = __builtin_bit_cast(uint_, v.x);                          \
    const uint_ u1 = __builtin_bit_cast(uint_, v.y);                          \
    const uint_ u2 = __builtin_bit_cast(uint_, v.z);                          \
    const uint_ u3 = __builtin_bit_cast(uint_, v.w);                          \
    uint2 hi, lo;                                                             \
    hi.x = (u0 >> 16) | (u1 & 0xffff0000u);                                   \
    hi.y = (u2 >> 16) | (u3 & 0xffff0000u);                                   \
    const float h0 = __builtin_bit_cast(float, u0 & 0xffff0000u);             \
    const float h1 = __builtin_bit_cast(float, u1 & 0xffff0000u);             \
    const float h2 = __builtin_bit_cast(float, u2 & 0xffff0000u);             \
    const float h3 = __builtin_bit_cast(float, u3 & 0xffff0000u);             \
    const uint_ l0 = __builtin_bit_cast(uint_, v.x - h0);                     \
    const uint_ l1 = __builtin_bit_cast(uint_, v.y - h1);                     \
    const uint_ l2 = __builtin_bit_cast(uint_, v.z - h2);                     \
    const uint_ l3 = __builtin_bit_cast(uint_, v.w - h3);                     \
    lo.x = (l0 >> 16) | (l1 & 0xffff0000u);                                   \
    lo.y = (l2 >> 16) | (l3 & 0xffff0000u);                                   \
    const int row = j * 32 + srow;                                            \
    const int idx = (row * 64 + scol) ^ ((row & 7) << 3);                     \
    *reinterpret_cast<uint2*>(&Hi[buf][idx]) = hi;                            \
    *reinterpret_cast<uint2*>(&Lo[buf][idx]) = lo;                            \
  }

  GLOAD(0)
  STAGE(0)
  __syncthreads();

  f32x4 acc[4][4] = {};

  for (int ks = 0; ks < NSTEP4; ++ks) {
    const int cur = ks & 1;
    if (ks + 1 < NSTEP4) GLOAD(ks + 1)
    __builtin_amdgcn_s_setprio(1);
#pragma unroll
    for (int kk = 0; kk < 2; ++kk) {
      const int kb = kk * 32 + (lane >> 4) * 8;
      bf16x8 ahi[4], bhi[4], blo[4];
#pragma unroll
      for (int m = 0; m < 4; ++m) {
        const int row = half * 128 + wr * 64 + m * 16 + (lane & 15);
        ahi[m] = *reinterpret_cast<const bf16x8*>(&Hi[cur][(row * 64 + kb) ^ ((row & 7) << 3)]);
      }
#pragma unroll
      for (int n = 0; n < 4; ++n) {
        const int row = wc * 64 + n * 16 + (lane & 15);
        bhi[n] = *reinterpret_cast<const bf16x8*>(&Hi[cur][(row * 64 + kb) ^ ((row & 7) << 3)]);
      }
#pragma unroll
      for (int m = 0; m < 4; ++m)
#pragma unroll
        for (int n = 0; n < 4; ++n)
          acc[m][n] = __builtin_amdgcn_mfma_f32_16x16x32_bf16(ahi[m], bhi[n], acc[m][n], 0, 0, 0);
#pragma unroll
      for (int n = 0; n < 4; ++n) {
        const int row = wc * 64 + n * 16 + (lane & 15);
        blo[n] = *reinterpret_cast<const bf16x8*>(&Lo[cur][(row * 64 + kb) ^ ((row & 7) << 3)]);
      }
#pragma unroll
      for (int m = 0; m < 4; ++m)
#pragma unroll
        for (int n = 0; n < 4; ++n)
          acc[m][n] = __builtin_amdgcn_mfma_f32_16x16x32_bf16(ahi[m], blo[n], acc[m][n], 0, 0, 0);
#pragma unroll
      for (int m = 0; m < 4; ++m) {
        const int row = half * 128 + wr * 64 + m * 16 + (lane & 15);
        bf16x8 alo = *reinterpret_cast<const bf16x8*>(&Lo[cur][(row * 64 + kb) ^ ((row & 7) << 3)]);
#pragma unroll
        for (int n = 0; n < 4; ++n)
          acc[m][n] = __builtin_amdgcn_mfma_f32_16x16x32_bf16(alo, bhi[n], acc[m][n], 0, 0, 0);
      }
    }
    __builtin_amdgcn_s_setprio(0);
    if (ks + 1 < NSTEP4) STAGE(cur ^ 1)
    __syncthreads();
  }
#undef GLOAD
#undef STAGE

#pragma unroll
  for (int j = 0; j < 8; ++j) {
#pragma unroll
    for (int off = 1; off < 16; off <<= 1) rs[j] += __shfl_xor(rs[j], off, 64);
  }
  if (half == 0 && (tid & 15) == 0) {
#pragma unroll
    for (int j = 0; j < 8; ++j)
      spart[((size_t)b * KC4 + kc) * 256 + j * 32 + srow] = rs[j];
  }

  float* gp = gpart + (size_t)bid * (128 * 256);
#pragma unroll
  for (int m = 0; m < 4; ++m) {
    const int row0 = wr * 64 + m * 16 + ((lane >> 4) << 2);
#pragma unroll
    for (int n = 0; n < 4; ++n) {
      const int col = wc * 64 + n * 16 + (lane & 15);
#pragma unroll
      for (int j = 0; j < 4; ++j)
        gp[(size_t)(row0 + j) * 256 + col] = acc[m][n][j];
    }
  }
}

// ---------------- k_reduce: G = sum_kc partials (float4, coalesced) ---------
__global__ __launch_bounds__(256) void k_reduce(const float* __restrict__ gpart,
                                                float* __restrict__ G) {
  const int t  = blockIdx.x * 256 + threadIdx.x;
  const int b  = t >> 14;
  const int i  = (t >> 6) & 255;
  const int j4 = (t & 63) * 4;
  const int hb = (i >> 7) * 128 + b * 16;
  const int il = i & 127;
  float4 s = make_float4(0.f, 0.f, 0.f, 0.f);
#pragma unroll
  for (int kc = 0; kc < KC4; ++kc) {
    const float4 v = *reinterpret_cast<const float4*>(
        &gpart[(size_t)(hb + kc) * (128 * 256) + (size_t)il * 256 + j4]);
    s.x += v.x; s.y += v.y; s.z += v.z; s.w += v.w;
  }
  *reinterpret_cast<float4*>(&G[((size_t)b * 256 + i) * 256 + j4]) = s;
}

// ---------------- k_transpose: 256x256 (w2 -> w2t) ----------------
__global__ __launch_bounds__(256) void k_transpose(const float* __restrict__ in,
                                                   float* __restrict__ outp) {
  __shared__ float t[32][33];
  const int bx = blockIdx.x & 7, by = blockIdx.x >> 3;
  const int tx = threadIdx.x & 31, ty = threadIdx.x >> 5;
#pragma unroll
  for (int i = 0; i < 32; i += 8)
    t[ty + i][tx] = in[(size_t)(by * 32 + ty + i) * 256 + bx * 32 + tx];
  __syncthreads();
#pragma unroll
  for (int i = 0; i < 32; i += 8)
    outp[(size_t)(bx * 32 + ty + i) * 256 + by * 32 + tx] = t[tx][ty + i];
}

// ---------------- k_u: s = reduce(spart); u1 = W1 s, u2 = W2 s --------------
__global__ __launch_bounds__(256) void k_u(const float* __restrict__ w1,
                                           const float* __restrict__ w2,
                                           const float* __restrict__ spart,
                                           float* __restrict__ u1,
                                           float* __restrict__ u2) {
  const int b = blockIdx.x;
  const int tid = threadIdx.x;
  __shared__ float sl[256];
  float sv = 0.f;
#pragma unroll
  for (int kc = 0; kc < KC4; ++kc) sv += spart[((size_t)b * KC4 + kc) * 256 + tid];
  sl[tid] = sv;
  __syncthreads();
  float a1 = 0.f, a2 = 0.f;
#pragma unroll 4
  for (int c = 0; c < 256; ++c) {
    a1 += w1[(size_t)tid * 256 + c] * sl[c];
    a2 += w2[(size_t)tid * 256 + c] * sl[c];
  }
  u1[b * 256 + tid] = a1;
  u2[b * 256 + tid] = a2;
}

// ---------------- k_smallmm: C[i,j] = sum_k A[i,k] B[k,j] (256^3) ----------
__global__ __launch_bounds__(256) void k_smallmm(const float* __restrict__ A, long asb,
                                                 const float* __restrict__ Bm, long bsb,
                                                 float* __restrict__ Cm, long csb) {
  const int b  = blockIdx.y;
  const int i0 = blockIdx.x * 8;
  const float* Ab = A  + (size_t)asb * b;
  const float* Bb = Bm + (size_t)bsb * b;
  float*       Cb = Cm + (size_t)csb * b;
  const int tid = threadIdx.x;
  __shared__ float arows[8][256];
#pragma unroll
  for (int rr = 0; rr < 8; ++rr) arows[rr][tid] = Ab[(size_t)(i0 + rr) * 256 + tid];
  __syncthreads();
  float acc[8] = {};
#pragma unroll 4
  for (int k = 0; k < 256; ++k) {
    const float bv = Bb[(size_t)k * 256 + tid];
#pragma unroll
    for (int rr = 0; rr < 8; ++rr) acc[rr] += arows[rr][k] * bv;
  }
#pragma unroll
  for (int rr = 0; rr < 8; ++rr) Cb[(size_t)(i0 + rr) * 256 + tid] = acc[rr];
}

// ---------------- k_softmax: logits finish + row softmax -> A (bf16) --------
__global__ __launch_bounds__(256) void k_softmax(const float* __restrict__ L,
                                                 const float* __restrict__ b1,
                                                 const float* __restrict__ b2,
                                                 const float* __restrict__ u1,
                                                 const float* __restrict__ u2,
                                                 unsigned short* __restrict__ Abf) {
  const int b = blockIdx.y, i = blockIdx.x, j = threadIdx.x;
  const size_t base = ((size_t)b * 256 + i) * 256;
  const float v = L[base + j] + u1[b * 256 + i] * b2[j] +
                  b1[i] * (u2[b * 256 + j] + 16384.f * b2[j]);
  const int lane = j & 63, wv = j >> 6;
  __shared__ float redm[4], reds[4];
  float m = v;
#pragma unroll
  for (int off = 32; off; off >>= 1) m = fmaxf(m, __shfl_xor(m, off, 64));
  if (lane == 0) redm[wv] = m;
  __syncthreads();
  m = fmaxf(fmaxf(redm[0], redm[1]), fmaxf(redm[2], redm[3]));
  const float e = __expf(v - m);
  float sm = e;
#pragma unroll
  for (int off = 32; off; off >>= 1) sm += __shfl_xor(sm, off, 64);
  if (lane == 0) reds[wv] = sm;
  __syncthreads();
  sm = (reds[0] + reds[1]) + (reds[2] + reds[3]);
  Abf[base + j] = f2bf(e / sm);
}

// ---------------- k_av: out = x + A @ X  (tile-pipelined, T14) --------------
// grid 512 = g(64) x b(8, low bits -> XCD-pinned); 512 thr / 8 waves.
// Each block: 4 n-tiles of 64 cols; X-loads for tile t+1 issued before the
// MFMA phase of tile t (in flight under ~2.5K cy of compute); Xt double-buf;
// swizzle s(r)=((r^(r>>2))&7)<<3 is conflict-free for BOTH writes and reads.
__global__ __launch_bounds__(512, 4) void k_av(const unsigned short* __restrict__ Abf,
                                               const float* __restrict__ x,
                                               float* __restrict__ out) {
  const int bid = blockIdx.x;
  const int b = bid & 7;
  const int nbase = (bid >> 3) * 256;
  const unsigned short* Ab = Abf + (size_t)b * 65536;
  const float* Xb = x + (size_t)b * C_ * NPIX;
  float* Ob = out + (size_t)b * C_ * NPIX;

  __shared__ __align__(16) unsigned short Xt[2][64 * 256];   // 2 x 32 KB

  const int tid = threadIdx.x;
  const int lane = tid & 63, w = tid >> 6;
  const int wc2 = w >> 1, wn = w & 1;
  const int dgrp = tid >> 4, d0 = dgrp * 8, nnb = (tid & 15) * 4;
  const float* xsb = Xb + (size_t)d0 * NPIX + nbase + nnb;

  float4 gld[8];

#define GLD(t)                                                                \
  _Pragma("unroll")                                                           \
  for (int r = 0; r < 8; ++r)                                                 \
    gld[r] = *reinterpret_cast<const float4*>(xsb + (size_t)r * NPIX + (t) * 64);

#define CONV(buf)                                                             \
  _Pragma("unroll")                                                           \
  for (int i = 0; i < 4; ++i) {                                               \
    uint4 v;                                                                  \
    v.x = (uint_)f2bf(fcomp(gld[0], i)) | ((uint_)f2bf(fcomp(gld[1], i)) << 16); \
    v.y = (uint_)f2bf(fcomp(gld[2], i)) | ((uint_)f2bf(fcomp(gld[3], i)) << 16); \
    v.z = (uint_)f2bf(fcomp(gld[4], i)) | ((uint_)f2bf(fcomp(gld[5], i)) << 16); \
    v.w = (uint_)f2bf(fcomp(gld[6], i)) | ((uint_)f2bf(fcomp(gld[7], i)) << 16); \
    const int row = nnb + i;                                                  \
    const int idx = (row * 256 + d0) ^ (((row ^ (row >> 2)) & 7) << 3);       \
    *reinterpret_cast<uint4*>(&Xt[buf][idx]) = v;                             \
  }

#define LOADA(kk, af)                                                         \
  _Pragma("unroll")                                                           \
  for (int m = 0; m < 4; ++m)                                                 \
    af[m] = *reinterpret_cast<const bf16x8*>(                                 \
        Ab + (size_t)(wc2 * 64 + m * 16 + (lane & 15)) * 256 + (kk) * 32 + kboff);

#define LOADB(kk, buf)                                                        \
  _Pragma("unroll")                                                           \
  for (int n = 0; n < 2; ++n) {                                               \
    const int nn2 = wn * 32 + n * 16 + (lane & 15);                           \
    bq[n] = *reinterpret_cast<const bf16x8*>(                                 \
        &Xt[buf][(nn2 * 256 + (kk) * 32 + kboff) ^ (((nn2 ^ (nn2 >> 2)) & 7) << 3)]); \
  }

#define MFMA8(af)                                                             \
  _Pragma("unroll")                                                           \
  for (int m = 0; m < 4; ++m)                                                 \
    _Pragma("unroll")                                                         \
    for (int n = 0; n < 2; ++n)                                               \
      acc[m][n] = __builtin_amdgcn_mfma_f32_16x16x32_bf16(af[m], bq[n], acc[m][n], 0, 0, 0);

  const int kboff = (lane >> 4) * 8;

  // prologue: tile 0 loads
  GLD(0)

#pragma unroll
  for (int t = 0; t < 4; ++t) {
    const int buf = t & 1;
    CONV(buf)
    __syncthreads();

    bf16x8 afA[4], afB[4], bq[2];
    LOADA(0, afA)
    if (t < 3) GLD(t + 1)          // T14: next tile's HBM loads in flight

    f32x4 acc[4][2] = {};
    __builtin_amdgcn_s_setprio(1);
#pragma unroll
    for (int kk = 0; kk < 8; ++kk) {
      LOADB(kk, buf)
      if (kk < 7) {
        if (kk & 1) { LOADA(kk + 1, afA) } else { LOADA(kk + 1, afB) }
      }
      if (kk & 1) { MFMA8(afB) } else { MFMA8(afA) }
    }
    __builtin_amdgcn_s_setprio(0);

    // epilogue: out = x + acc (x re-read L2-hot: staged this tile just now)
#pragma unroll
    for (int m = 0; m < 4; ++m) {
      const int row0 = wc2 * 64 + m * 16 + ((lane >> 4) << 2);
#pragma unroll
      for (int n = 0; n < 2; ++n) {
        const int col = nbase + t * 64 + wn * 32 + n * 16 + (lane & 15);
#pragma unroll
        for (int j = 0; j < 4; ++j) {
          const size_t a = (size_t)(row0 + j) * NPIX + col;
          Ob[a] = Xb[a] + acc[m][n][j];
        }
      }
    }
  }
#undef GLD
#undef CONV
#undef LOADA
#undef LOADB
#undef MFMA8
}

extern "C" void kernel_launch(void* const* d_in, const int* in_sizes, int n_in,
                              void* d_out, int out_size, void* d_ws, size_t ws_size,
                              hipStream_t stream) {
  const float* x  = (const float*)d_in[0];
  const float* w1 = (const float*)d_in[1];
  const float* b1 = (const float*)d_in[2];
  const float* w2 = (const float*)d_in[3];
  const float* b2 = (const float*)d_in[4];
  float* out = (float*)d_out;
  char* ws = (char*)d_ws;

  // Gram partials live in d_out (33.5 MB of its 64 MB) — consumed by k_reduce
  // before k_av overwrites d_out with the real output.
  float* gpart = out;

  constexpr size_t G_OFF     = 0;
  constexpr size_t T1_OFF    = G_OFF   + (size_t)B_ * C_ * C_ * 4;
  constexpr size_t L_OFF     = T1_OFF  + (size_t)B_ * C_ * C_ * 4;
  constexpr size_t W2T_OFF   = L_OFF   + (size_t)B_ * C_ * C_ * 4;
  constexpr size_t SPART_OFF = W2T_OFF + (size_t)C_ * C_ * 4;
  constexpr size_t U1_OFF    = SPART_OFF + (size_t)B_ * KC4 * C_ * 4;
  constexpr size_t U2_OFF    = U1_OFF  + (size_t)B_ * C_ * 4;
  constexpr size_t ABF_OFF   = U2_OFF  + (size_t)B_ * C_ * 4;

  float* G     = (float*)(ws + G_OFF);
  float* T1    = (float*)(ws + T1_OFF);
  float* L     = (float*)(ws + L_OFF);
  float* w2t   = (float*)(ws + W2T_OFF);
  float* spart = (float*)(ws + SPART_OFF);
  float* u1    = (float*)(ws + U1_OFF);
  float* u2    = (float*)(ws + U2_OFF);
  unsigned short* Abf = (unsigned short*)(ws + ABF_OFF);

  k_transpose<<<64, 256, 0, stream>>>(w2, w2t);
  k_gram     <<<256, 512, 0, stream>>>(x, gpart, spart);
  k_reduce   <<<512, 256, 0, stream>>>(gpart, G);
  k_u        <<<B_, 256, 0, stream>>>(w1, w2, spart, u1, u2);
  k_smallmm  <<<dim3(32, B_), 256, 0, stream>>>(w1, 0, G, C_ * C_, T1, C_ * C_);
  k_smallmm  <<<dim3(32, B_), 256, 0, stream>>>(T1, C_ * C_, w2t, 0, L, C_ * C_);
  k_softmax  <<<dim3(C_, B_), 256, 0, stream>>>(L, b1, b2, u1, u2, Abf);
  k_av       <<<512, 512, 0, stream>>>(Abf, x, out);
}

// Round 6
// 212.889 us; speedup vs baseline: 1.6667x; 1.6667x over previous
//
#include <hip/hip_runtime.h>
#include <hip/hip_bf16.h>

// Problem sizes (fixed)
#define B_    8
#define C_    256
#define NPIX  16384           // 128*128
#define BK    64
#define KC4   16              // K-chunks for gram
#define KCH4  (NPIX / KC4)    // 1024 k per block
#define NSTEP4 (KCH4 / BK)    // 16 steps per block

typedef __attribute__((ext_vector_type(8))) short bf16x8;
typedef __attribute__((ext_vector_type(4))) float f32x4;
typedef unsigned int uint_;

__device__ __forceinline__ unsigned short f2bf(float x) {
  unsigned int u = __builtin_bit_cast(unsigned int, x);
  u = (u + 0x7fffu + ((u >> 16) & 1u)) >> 16;   // RTNE
  return (unsigned short)u;
}
__device__ __forceinline__ float fcomp(const float4& v, int i) {
  switch (i) { case 0: return v.x; case 1: return v.y; case 2: return v.z; default: return v.w; }
}

// ---------------- k_gram: partial Gram, NO atomics (unchanged, r4) ---------
__global__ __launch_bounds__(512, 2) void k_gram(const float* __restrict__ x,
                                                 float* __restrict__ gpart,
                                                 float* __restrict__ spart) {
  const int bid  = blockIdx.x;
  const int half = bid >> 7;
  const int b    = (bid >> 4) & 7;
  const int kc   = bid & 15;
  const float* X = x + (size_t)b * C_ * NPIX + kc * KCH4;

  __shared__ __align__(16) unsigned short Hi[2][256 * 64];
  __shared__ __align__(16) unsigned short Lo[2][256 * 64];

  const int tid  = threadIdx.x;
  const int lane = tid & 63;
  const int w    = tid >> 6;
  const int wr   = w >> 2;
  const int wc   = w & 3;

  const int srow = tid >> 4;
  const int scol = (tid & 15) * 4;
  const float* sp = X + (size_t)srow * NPIX + scol;

  float rs[8] = {};
  float4 g[8];

#define GLOAD(ks)                                                             \
  _Pragma("unroll")                                                           \
  for (int j = 0; j < 8; ++j)                                                 \
    g[j] = *reinterpret_cast<const float4*>(sp + (size_t)j * 32 * NPIX + (ks) * BK);

#define STAGE(buf)                                                            \
  _Pragma("unroll")                                                           \
  for (int j = 0; j < 8; ++j) {                                               \
    const float4 v = g[j];                                                    \
    rs[j] += (v.x + v.y) + (v.z + v.w);                                       \
    const uint_ u0 = __builtin_bit_cast(uint_, v.x);                          \
    const uint_ u1 = __builtin_bit_cast(uint_, v.y);                          \
    const uint_ u2 = __builtin_bit_cast(uint_, v.z);                          \
    const uint_ u3 = __builtin_bit_cast(uint_, v.w);                          \
    uint2 hi, lo;                                                             \
    hi.x = (u0 >> 16) | (u1 & 0xffff0000u);                                   \
    hi.y = (u2 >> 16) | (u3 & 0xffff0000u);                                   \
    const float h0 = __builtin_bit_cast(float, u0 & 0xffff0000u);             \
    const float h1 = __builtin_bit_cast(float, u1 & 0xffff0000u);             \
    const float h2 = __builtin_bit_cast(float, u2 & 0xffff0000u);             \
    const float h3 = __builtin_bit_cast(float, u3 & 0xffff0000u);             \
    const uint_ l0 = __builtin_bit_cast(uint_, v.x - h0);                     \
    const uint_ l1 = __builtin_bit_cast(uint_, v.y - h1);                     \
    const uint_ l2 = __builtin_bit_cast(uint_, v.z - h2);                     \
    const uint_ l3 = __builtin_bit_cast(uint_, v.w - h3);                     \
    lo.x = (l0 >> 16) | (l1 & 0xffff0000u);                                   \
    lo.y = (l2 >> 16) | (l3 & 0xffff0000u);                                   \
    const int row = j * 32 + srow;                                            \
    const int idx = (row * 64 + scol) ^ ((row & 7) << 3);                     \
    *reinterpret_cast<uint2*>(&Hi[buf][idx]) = hi;                            \
    *reinterpret_cast<uint2*>(&Lo[buf][idx]) = lo;                            \
  }

  GLOAD(0)
  STAGE(0)
  __syncthreads();

  f32x4 acc[4][4] = {};

  for (int ks = 0; ks < NSTEP4; ++ks) {
    const int cur = ks & 1;
    if (ks + 1 < NSTEP4) GLOAD(ks + 1)
    __builtin_amdgcn_s_setprio(1);
#pragma unroll
    for (int kk = 0; kk < 2; ++kk) {
      const int kb = kk * 32 + (lane >> 4) * 8;
      bf16x8 ahi[4], bhi[4], blo[4];
#pragma unroll
      for (int m = 0; m < 4; ++m) {
        const int row = half * 128 + wr * 64 + m * 16 + (lane & 15);
        ahi[m] = *reinterpret_cast<const bf16x8*>(&Hi[cur][(row * 64 + kb) ^ ((row & 7) << 3)]);
      }
#pragma unroll
      for (int n = 0; n < 4; ++n) {
        const int row = wc * 64 + n * 16 + (lane & 15);
        bhi[n] = *reinterpret_cast<const bf16x8*>(&Hi[cur][(row * 64 + kb) ^ ((row & 7) << 3)]);
      }
#pragma unroll
      for (int m = 0; m < 4; ++m)
#pragma unroll
        for (int n = 0; n < 4; ++n)
          acc[m][n] = __builtin_amdgcn_mfma_f32_16x16x32_bf16(ahi[m], bhi[n], acc[m][n], 0, 0, 0);
#pragma unroll
      for (int n = 0; n < 4; ++n) {
        const int row = wc * 64 + n * 16 + (lane & 15);
        blo[n] = *reinterpret_cast<const bf16x8*>(&Lo[cur][(row * 64 + kb) ^ ((row & 7) << 3)]);
      }
#pragma unroll
      for (int m = 0; m < 4; ++m)
#pragma unroll
        for (int n = 0; n < 4; ++n)
          acc[m][n] = __builtin_amdgcn_mfma_f32_16x16x32_bf16(ahi[m], blo[n], acc[m][n], 0, 0, 0);
#pragma unroll
      for (int m = 0; m < 4; ++m) {
        const int row = half * 128 + wr * 64 + m * 16 + (lane & 15);
        bf16x8 alo = *reinterpret_cast<const bf16x8*>(&Lo[cur][(row * 64 + kb) ^ ((row & 7) << 3)]);
#pragma unroll
        for (int n = 0; n < 4; ++n)
          acc[m][n] = __builtin_amdgcn_mfma_f32_16x16x32_bf16(alo, bhi[n], acc[m][n], 0, 0, 0);
      }
    }
    __builtin_amdgcn_s_setprio(0);
    if (ks + 1 < NSTEP4) STAGE(cur ^ 1)
    __syncthreads();
  }
#undef GLOAD
#undef STAGE

#pragma unroll
  for (int j = 0; j < 8; ++j) {
#pragma unroll
    for (int off = 1; off < 16; off <<= 1) rs[j] += __shfl_xor(rs[j], off, 64);
  }
  if (half == 0 && (tid & 15) == 0) {
#pragma unroll
    for (int j = 0; j < 8; ++j)
      spart[((size_t)b * KC4 + kc) * 256 + j * 32 + srow] = rs[j];
  }

  float* gp = gpart + (size_t)bid * (128 * 256);
#pragma unroll
  for (int m = 0; m < 4; ++m) {
    const int row0 = wr * 64 + m * 16 + ((lane >> 4) << 2);
#pragma unroll
    for (int n = 0; n < 4; ++n) {
      const int col = wc * 64 + n * 16 + (lane & 15);
#pragma unroll
      for (int j = 0; j < 4; ++j)
        gp[(size_t)(row0 + j) * 256 + col] = acc[m][n][j];
    }
  }
}

// ---------------- k_reduce: G = sum_kc partials (float4, coalesced) ---------
__global__ __launch_bounds__(256) void k_reduce(const float* __restrict__ gpart,
                                                float* __restrict__ G) {
  const int t  = blockIdx.x * 256 + threadIdx.x;
  const int b  = t >> 14;
  const int i  = (t >> 6) & 255;
  const int j4 = (t & 63) * 4;
  const int hb = (i >> 7) * 128 + b * 16;
  const int il = i & 127;
  float4 s = make_float4(0.f, 0.f, 0.f, 0.f);
#pragma unroll
  for (int kc = 0; kc < KC4; ++kc) {
    const float4 v = *reinterpret_cast<const float4*>(
        &gpart[(size_t)(hb + kc) * (128 * 256) + (size_t)il * 256 + j4]);
    s.x += v.x; s.y += v.y; s.z += v.z; s.w += v.w;
  }
  *reinterpret_cast<float4*>(&G[((size_t)b * 256 + i) * 256 + j4]) = s;
}

// ---------------- k_transpose: 256x256 (w2 -> w2t) ----------------
__global__ __launch_bounds__(256) void k_transpose(const float* __restrict__ in,
                                                   float* __restrict__ outp) {
  __shared__ float t[32][33];
  const int bx = blockIdx.x & 7, by = blockIdx.x >> 3;
  const int tx = threadIdx.x & 31, ty = threadIdx.x >> 5;
#pragma unroll
  for (int i = 0; i < 32; i += 8)
    t[ty + i][tx] = in[(size_t)(by * 32 + ty + i) * 256 + bx * 32 + tx];
  __syncthreads();
#pragma unroll
  for (int i = 0; i < 32; i += 8)
    outp[(size_t)(bx * 32 + ty + i) * 256 + by * 32 + tx] = t[tx][ty + i];
}

// ---------------- k_u: s = reduce(spart); u1 = W1 s, u2 = W2 s --------------
__global__ __launch_bounds__(256) void k_u(const float* __restrict__ w1,
                                           const float* __restrict__ w2,
                                           const float* __restrict__ spart,
                                           float* __restrict__ u1,
                                           float* __restrict__ u2) {
  const int b = blockIdx.x;
  const int tid = threadIdx.x;
  __shared__ float sl[256];
  float sv = 0.f;
#pragma unroll
  for (int kc = 0; kc < KC4; ++kc) sv += spart[((size_t)b * KC4 + kc) * 256 + tid];
  sl[tid] = sv;
  __syncthreads();
  float a1 = 0.f, a2 = 0.f;
#pragma unroll 4
  for (int c = 0; c < 256; ++c) {
    a1 += w1[(size_t)tid * 256 + c] * sl[c];
    a2 += w2[(size_t)tid * 256 + c] * sl[c];
  }
  u1[b * 256 + tid] = a1;
  u2[b * 256 + tid] = a2;
}

// ---------------- k_smallmm: C[i,j] = sum_k A[i,k] B[k,j] (256^3) ----------
__global__ __launch_bounds__(256) void k_smallmm(const float* __restrict__ A, long asb,
                                                 const float* __restrict__ Bm, long bsb,
                                                 float* __restrict__ Cm, long csb) {
  const int b  = blockIdx.y;
  const int i0 = blockIdx.x * 8;
  const float* Ab = A  + (size_t)asb * b;
  const float* Bb = Bm + (size_t)bsb * b;
  float*       Cb = Cm + (size_t)csb * b;
  const int tid = threadIdx.x;
  __shared__ float arows[8][256];
#pragma unroll
  for (int rr = 0; rr < 8; ++rr) arows[rr][tid] = Ab[(size_t)(i0 + rr) * 256 + tid];
  __syncthreads();
  float acc[8] = {};
#pragma unroll 4
  for (int k = 0; k < 256; ++k) {
    const float bv = Bb[(size_t)k * 256 + tid];
#pragma unroll
    for (int rr = 0; rr < 8; ++rr) acc[rr] += arows[rr][k] * bv;
  }
#pragma unroll
  for (int rr = 0; rr < 8; ++rr) Cb[(size_t)(i0 + rr) * 256 + tid] = acc[rr];
}

// ------- k_softmax: logits finish + softmax; store Abf = softmax + I --------
// Folding the residual into the matrix (out = (I + A) X) lets k_av's epilogue
// be pure stores — no x re-read, no L2 dependence.
__global__ __launch_bounds__(256) void k_softmax(const float* __restrict__ L,
                                                 const float* __restrict__ b1,
                                                 const float* __restrict__ b2,
                                                 const float* __restrict__ u1,
                                                 const float* __restrict__ u2,
                                                 unsigned short* __restrict__ Abf) {
  const int b = blockIdx.y, i = blockIdx.x, j = threadIdx.x;
  const size_t base = ((size_t)b * 256 + i) * 256;
  const float v = L[base + j] + u1[b * 256 + i] * b2[j] +
                  b1[i] * (u2[b * 256 + j] + 16384.f * b2[j]);
  const int lane = j & 63, wv = j >> 6;
  __shared__ float redm[4], reds[4];
  float m = v;
#pragma unroll
  for (int off = 32; off; off >>= 1) m = fmaxf(m, __shfl_xor(m, off, 64));
  if (lane == 0) redm[wv] = m;
  __syncthreads();
  m = fmaxf(fmaxf(redm[0], redm[1]), fmaxf(redm[2], redm[3]));
  const float e = __expf(v - m);
  float sm = e;
#pragma unroll
  for (int off = 32; off; off >>= 1) sm += __shfl_xor(sm, off, 64);
  if (lane == 0) reds[wv] = sm;
  __syncthreads();
  sm = (reds[0] + reds[1]) + (reds[2] + reds[3]);
  float p = e / sm;
  if (j == i) p += 1.0f;                 // residual folded into diagonal
  Abf[base + j] = f2bf(p);
}

// ---------------- k_av: out = (I+A) @ X  (pure-store epilogue) --------------
// grid 4096 = pxtile(512) x b(8, low bits -> XCD-pinned); 256 thr / 4 waves.
// Tile: 32 px (M) x 256 ch (N), K = 256 d. Xt [px][d] bf16 16 KB, bijective
// swizzle. Operand-swapped MFMA: D rows = px -> float4 stores (lane clusters
// cover 64B contiguous). No epilogue reads.
__global__ __launch_bounds__(256, 4) void k_av(const unsigned short* __restrict__ Abf,
                                               const float* __restrict__ x,
                                               float* __restrict__ out) {
  const int bid = blockIdx.x;
  const int b = bid & 7;
  const int nbase = (bid >> 3) * 32;
  const unsigned short* Ab = Abf + (size_t)b * 65536;
  const float* Xb = x + (size_t)b * C_ * NPIX;
  float* Ob = out + (size_t)b * C_ * NPIX;

  __shared__ __align__(16) unsigned short Xt[32 * 256];   // [px][d], 16 KB

  const int tid = threadIdx.x;
  const int lane = tid & 63, w = tid >> 6;   // w = ch-block 0..3

  // stage: thread covers d-quad (tid>>3)*4 (+128h), px-quad (tid&7)*4.
  // Global instr: 8 d-rows x 128B = full lines.
  {
    const int pq = (tid & 7) * 4;
    const int dq = (tid >> 3) * 4;
#pragma unroll
    for (int h = 0; h < 2; ++h) {
      const int d = dq + h * 128;
      const float* xs = Xb + (size_t)d * NPIX + nbase + pq;
      const float4 r0 = *reinterpret_cast<const float4*>(xs);
      const float4 r1 = *reinterpret_cast<const float4*>(xs + NPIX);
      const float4 r2 = *reinterpret_cast<const float4*>(xs + 2 * NPIX);
      const float4 r3 = *reinterpret_cast<const float4*>(xs + 3 * NPIX);
#pragma unroll
      for (int i = 0; i < 4; ++i) {
        const int px = pq + i;
        ushort4 v = make_ushort4(f2bf(fcomp(r0, i)), f2bf(fcomp(r1, i)),
                                 f2bf(fcomp(r2, i)), f2bf(fcomp(r3, i)));
        const int idx = (px * 256 + d) ^ (((px ^ (px >> 2)) & 7) << 3);
        *reinterpret_cast<ushort4*>(&Xt[idx]) = v;
      }
    }
  }
  __syncthreads();

  const int kboff = (lane >> 4) * 8;
  f32x4 acc[4][2] = {};                    // acc[ch-frag m][px-frag n]
  bf16x8 afA[4], afB[4], bq[2];

#define LOADA(kk, af)                                                         \
  _Pragma("unroll")                                                           \
  for (int m = 0; m < 4; ++m)                                                 \
    af[m] = *reinterpret_cast<const bf16x8*>(                                 \
        Ab + (size_t)(w * 64 + m * 16 + (lane & 15)) * 256 + (kk) * 32 + kboff);

#define LOADB(kk)                                                             \
  _Pragma("unroll")                                                           \
  for (int n = 0; n < 2; ++n) {                                               \
    const int px = n * 16 + (lane & 15);                                      \
    bq[n] = *reinterpret_cast<const bf16x8*>(                                 \
        &Xt[(px * 256 + (kk) * 32 + kboff) ^ (((px ^ (px >> 2)) & 7) << 3)]); \
  }

#define MFMA8(af)                                                             \
  _Pragma("unroll")                                                           \
  for (int m = 0; m < 4; ++m)                                                 \
    _Pragma("unroll")                                                         \
    for (int n = 0; n < 2; ++n)                                               \
      acc[m][n] = __builtin_amdgcn_mfma_f32_16x16x32_bf16(bq[n], af[m], acc[m][n], 0, 0, 0);

  LOADA(0, afA)
#pragma unroll
  for (int kk = 0; kk < 8; ++kk) {
    LOADB(kk)
    if (kk < 7) {
      if (kk & 1) { LOADA(kk + 1, afA) } else { LOADA(kk + 1, afB) }
    }
    if (kk & 1) { MFMA8(afB) } else { MFMA8(afA) }
  }
#undef LOADA
#undef LOADB
#undef MFMA8

  // epilogue: pure float4 stores; lane clusters (lane&15 fixed) cover 64B runs
#pragma unroll
  for (int m = 0; m < 4; ++m) {
    const int ch = w * 64 + m * 16 + (lane & 15);
    float* orow = Ob + (size_t)ch * NPIX + nbase;
#pragma unroll
    for (int n = 0; n < 2; ++n) {
      const int p0 = n * 16 + ((lane >> 4) << 2);
      *reinterpret_cast<float4*>(orow + p0) = *reinterpret_cast<const float4*>(&acc[m][n]);
    }
  }
}

extern "C" void kernel_launch(void* const* d_in, const int* in_sizes, int n_in,
                              void* d_out, int out_size, void* d_ws, size_t ws_size,
                              hipStream_t stream) {
  const float* x  = (const float*)d_in[0];
  const float* w1 = (const float*)d_in[1];
  const float* b1 = (const float*)d_in[2];
  const float* w2 = (const float*)d_in[3];
  const float* b2 = (const float*)d_in[4];
  float* out = (float*)d_out;
  char* ws = (char*)d_ws;

  // Gram partials live in d_out (33.5 MB of its 64 MB) — consumed by k_reduce
  // before k_av overwrites d_out with the real output.
  float* gpart = out;

  constexpr size_t G_OFF     = 0;
  constexpr size_t T1_OFF    = G_OFF   + (size_t)B_ * C_ * C_ * 4;
  constexpr size_t L_OFF     = T1_OFF  + (size_t)B_ * C_ * C_ * 4;
  constexpr size_t W2T_OFF   = L_OFF   + (size_t)B_ * C_ * C_ * 4;
  constexpr size_t SPART_OFF = W2T_OFF + (size_t)C_ * C_ * 4;
  constexpr size_t U1_OFF    = SPART_OFF + (size_t)B_ * KC4 * C_ * 4;
  constexpr size_t U2_OFF    = U1_OFF  + (size_t)B_ * C_ * 4;
  constexpr size_t ABF_OFF   = U2_OFF  + (size_t)B_ * C_ * 4;

  float* G     = (float*)(ws + G_OFF);
  float* T1    = (float*)(ws + T1_OFF);
  float* L     = (float*)(ws + L_OFF);
  float* w2t   = (float*)(ws + W2T_OFF);
  float* spart = (float*)(ws + SPART_OFF);
  float* u1    = (float*)(ws + U1_OFF);
  float* u2    = (float*)(ws + U2_OFF);
  unsigned short* Abf = (unsigned short*)(ws + ABF_OFF);

  k_transpose<<<64, 256, 0, stream>>>(w2, w2t);
  k_gram     <<<256, 512, 0, stream>>>(x, gpart, spart);
  k_reduce   <<<512, 256, 0, stream>>>(gpart, G);
  k_u        <<<B_, 256, 0, stream>>>(w1, w2, spart, u1, u2);
  k_smallmm  <<<dim3(32, B_), 256, 0, stream>>>(w1, 0, G, C_ * C_, T1, C_ * C_);
  k_smallmm  <<<dim3(32, B_), 256, 0, stream>>>(T1, C_ * C_, w2t, 0, L, C_ * C_);
  k_softmax  <<<dim3(C_, B_), 256, 0, stream>>>(L, b1, b2, u1, u2, Abf);
  k_av       <<<4096, 256, 0, stream>>>(Abf, x, out);
}